// Round 1
// baseline (824.272 us; speedup 1.0000x reference)
//
#include <hip/hip_runtime.h>

#define NN 100000
#define NE 1600000
#define IN_CH 128
#define HID_CH 64
#define OUT_CH 32

__global__ void k_init_deg(int* __restrict__ deg) {
    int i = blockIdx.x * blockDim.x + threadIdx.x;
    if (i < NN) deg[i] = 1;  // self-loop
}

__global__ void k_deg(const int* __restrict__ da, int* __restrict__ deg) {
    int e = blockIdx.x * blockDim.x + threadIdx.x;
    if (e < NE) atomicAdd(&deg[da[e]], 1);
}

__global__ void k_rs(const int* __restrict__ deg, float* __restrict__ rs) {
    int i = blockIdx.x * blockDim.x + threadIdx.x;
    if (i < NN) rs[i] = rsqrtf((float)deg[i]);
}

// xs[n][c] = ((x[n] @ W1 + b1)[c]) * rs[n]; agg1 seeded with self-loop term.
// One wave (64 lanes) per node; lane = hidden channel.
__global__ void k_gemm1(const float* __restrict__ x, const float* __restrict__ W1,
                        const float* __restrict__ b1, const float* __restrict__ rs,
                        float* __restrict__ xs, float* __restrict__ agg1) {
    int lane = threadIdx.x & 63;
    int n = (blockIdx.x * blockDim.x + threadIdx.x) >> 6;
    if (n >= NN) return;
    const float4* xr = (const float4*)(x + (size_t)n * IN_CH);
    float acc = b1[lane];
#pragma unroll
    for (int k4 = 0; k4 < IN_CH / 4; ++k4) {
        float4 xv = xr[k4];
        int k = k4 * 4;
        acc = fmaf(xv.x, W1[(k + 0) * HID_CH + lane], acc);
        acc = fmaf(xv.y, W1[(k + 1) * HID_CH + lane], acc);
        acc = fmaf(xv.z, W1[(k + 2) * HID_CH + lane], acc);
        acc = fmaf(xv.w, W1[(k + 3) * HID_CH + lane], acc);
    }
    float v = acc * rs[n];
    xs[(size_t)n * HID_CH + lane] = v;
    agg1[(size_t)n * HID_CH + lane] = v;
}

// One wave per edge: 64 coalesced gathers + 64 coalesced float atomics.
__global__ void k_scatter1(const int* __restrict__ sa, const int* __restrict__ da,
                           const float* __restrict__ xs, float* __restrict__ agg1) {
    int gid = blockIdx.x * blockDim.x + threadIdx.x;
    int e = gid >> 6;
    int c = gid & 63;
    if (e >= NE) return;
    int s = sa[e], d = da[e];
    atomicAdd(&agg1[(size_t)d * HID_CH + c], xs[(size_t)s * HID_CH + c]);
}

// h[n] = relu(agg1[n]*rs[n]); ys[n] = (h[n]@W2 + b2)*rs[n]; agg2(d_out) seeded.
// 32 threads per node; c = output channel.
__global__ void k_gemm2(const float* __restrict__ agg1, const float* __restrict__ W2,
                        const float* __restrict__ b2, const float* __restrict__ rs,
                        float* __restrict__ ys, float* __restrict__ agg2) {
    int t = blockIdx.x * blockDim.x + threadIdx.x;
    int n = t >> 5;
    int c = t & 31;
    if (n >= NN) return;
    float rn = rs[n];
    float acc = b2[c];
    const float* a = agg1 + (size_t)n * HID_CH;
#pragma unroll
    for (int k = 0; k < HID_CH; ++k) {
        float h = a[k] * rn;
        h = h > 0.0f ? h : 0.0f;
        acc = fmaf(h, W2[k * OUT_CH + c], acc);
    }
    float v = acc * rn;
    ys[(size_t)n * OUT_CH + c] = v;
    agg2[(size_t)n * OUT_CH + c] = v;
}

// Half-wave (32 lanes) per edge.
__global__ void k_scatter2(const int* __restrict__ sa, const int* __restrict__ da,
                           const float* __restrict__ ys, float* __restrict__ agg2) {
    int gid = blockIdx.x * blockDim.x + threadIdx.x;
    int e = gid >> 5;
    int c = gid & 31;
    if (e >= NE) return;
    int s = sa[e], d = da[e];
    atomicAdd(&agg2[(size_t)d * OUT_CH + c], ys[(size_t)s * OUT_CH + c]);
}

__global__ void k_final(const float* __restrict__ rs, float* __restrict__ out) {
    int i = blockIdx.x * blockDim.x + threadIdx.x;
    if (i < NN * OUT_CH) out[i] *= rs[i >> 5];  // i / OUT_CH
}

extern "C" void kernel_launch(void* const* d_in, const int* in_sizes, int n_in,
                              void* d_out, int out_size, void* d_ws, size_t ws_size,
                              hipStream_t stream) {
    const float* x  = (const float*)d_in[0];
    const int*   ei = (const int*)d_in[1];      // (2, E) int32: row 0 = src, row 1 = dst
    const float* W1 = (const float*)d_in[2];
    const float* b1 = (const float*)d_in[3];
    const float* W2 = (const float*)d_in[4];
    const float* b2 = (const float*)d_in[5];
    const int* sa = ei;
    const int* da = ei + NE;

    char* ws = (char*)d_ws;
    size_t off = 0;
    int*   deg  = (int*)(ws + off);   off += (size_t)NN * sizeof(int);      // 400000
    float* rs   = (float*)(ws + off); off += (size_t)NN * sizeof(float);    // 400000
    float* xs   = (float*)(ws + off); off += (size_t)NN * HID_CH * sizeof(float); // 25.6MB
    float* agg1 = (float*)(ws + off); off += (size_t)NN * HID_CH * sizeof(float); // 25.6MB
    float* ys   = (float*)(ws + off); off += (size_t)NN * OUT_CH * sizeof(float); // 12.8MB
    float* agg2 = (float*)d_out;

    const int B = 256;
    k_init_deg<<<(NN + B - 1) / B, B, 0, stream>>>(deg);
    k_deg<<<(NE + B - 1) / B, B, 0, stream>>>(da, deg);
    k_rs<<<(NN + B - 1) / B, B, 0, stream>>>(deg, rs);

    // GEMM1: one wave per node -> 4 nodes per 256-thread block
    k_gemm1<<<(NN + 3) / 4, B, 0, stream>>>(x, W1, b1, rs, xs, agg1);

    // scatter1: one wave per edge
    {
        long long threads = (long long)NE * 64;
        k_scatter1<<<(int)((threads + B - 1) / B), B, 0, stream>>>(sa, da, xs, agg1);
    }

    // GEMM2: 32 threads per node -> 8 nodes per block
    k_gemm2<<<(NN + 7) / 8, B, 0, stream>>>(agg1, W2, b2, rs, ys, agg2);

    // scatter2: 32 threads per edge
    {
        long long threads = (long long)NE * 32;
        k_scatter2<<<(int)((threads + B - 1) / B), B, 0, stream>>>(sa, da, ys, agg2);
    }

    k_final<<<(NN * OUT_CH + B - 1) / B, B, 0, stream>>>(rs, agg2);
}

// Round 2
// 536.377 us; speedup vs baseline: 1.5367x; 1.5367x over previous
//
#include <hip/hip_runtime.h>

#define NN 100000
#define NE 1600000
#define IN_CH 128
#define HID_CH 64
#define OUT_CH 32
#define SCAN_CHUNK 1024
#define NBLK_SCAN ((NN + SCAN_CHUNK - 1) / SCAN_CHUNK)   // 98

// ---- degree histogram (no self-loop; +1 applied in k_rs) ----
__global__ void k_hist(const int* __restrict__ da, int* __restrict__ hist) {
    int e = blockIdx.x * blockDim.x + threadIdx.x;
    if (e < NE) atomicAdd(&hist[da[e]], 1);
}

__global__ void k_rs(const int* __restrict__ hist, float* __restrict__ rs) {
    int i = blockIdx.x * blockDim.x + threadIdx.x;
    if (i < NN) rs[i] = rsqrtf((float)(hist[i] + 1));
}

// ---- exclusive scan of hist -> rowptr (3 kernels) ----
__global__ void k_scan1(const int* __restrict__ hist, int* __restrict__ part,
                        int* __restrict__ bsum) {
    __shared__ int lds[256];
    int t = threadIdx.x;
    int base = blockIdx.x * SCAN_CHUNK + t * 4;
    int v0 = 0, v1 = 0, v2 = 0, v3 = 0;
    if (base + 0 < NN) v0 = hist[base + 0];
    if (base + 1 < NN) v1 = hist[base + 1];
    if (base + 2 < NN) v2 = hist[base + 2];
    if (base + 3 < NN) v3 = hist[base + 3];
    int s = v0 + v1 + v2 + v3;
    lds[t] = s;
    __syncthreads();
    for (int off = 1; off < 256; off <<= 1) {
        int x = (t >= off) ? lds[t - off] : 0;
        __syncthreads();
        lds[t] += x;
        __syncthreads();
    }
    int excl = lds[t] - s;
    if (base + 0 < NN) part[base + 0] = excl;
    if (base + 1 < NN) part[base + 1] = excl + v0;
    if (base + 2 < NN) part[base + 2] = excl + v0 + v1;
    if (base + 3 < NN) part[base + 3] = excl + v0 + v1 + v2;
    if (t == 255) bsum[blockIdx.x] = lds[255];
}

__global__ void k_scan2(int* __restrict__ bsum) {  // single block, 128 threads
    __shared__ int lds[128];
    int t = threadIdx.x;
    int v = (t < NBLK_SCAN) ? bsum[t] : 0;
    lds[t] = v;
    __syncthreads();
    for (int off = 1; off < 128; off <<= 1) {
        int x = (t >= off) ? lds[t - off] : 0;
        __syncthreads();
        lds[t] += x;
        __syncthreads();
    }
    if (t < NBLK_SCAN) bsum[t] = lds[t] - v;  // exclusive
}

__global__ void k_scan3(const int* __restrict__ part, const int* __restrict__ bsum,
                        int* __restrict__ rowptr, int* __restrict__ cursor) {
    int i = blockIdx.x * blockDim.x + threadIdx.x;
    if (i < NN) {
        int v = part[i] + bsum[i >> 10];
        rowptr[i] = v;
        cursor[i] = v;
    }
    if (i == NN) rowptr[NN] = NE;
}

__global__ void k_fill(const int* __restrict__ sa, const int* __restrict__ da,
                       int* __restrict__ cursor, int* __restrict__ col) {
    int e = blockIdx.x * blockDim.x + threadIdx.x;
    if (e < NE) {
        int p = atomicAdd(&cursor[da[e]], 1);
        col[p] = sa[e];
    }
}

// ---- xs[n][c] = ((x[n] @ W1 + b1)[c]) * rs[n]; one wave per node ----
__global__ void k_gemm1(const float* __restrict__ x, const float* __restrict__ W1,
                        const float* __restrict__ b1, const float* __restrict__ rs,
                        float* __restrict__ xs) {
    int lane = threadIdx.x & 63;
    int n = (blockIdx.x * blockDim.x + threadIdx.x) >> 6;
    if (n >= NN) return;
    const float4* xr = (const float4*)(x + (size_t)n * IN_CH);
    float acc = b1[lane];
#pragma unroll
    for (int k4 = 0; k4 < IN_CH / 4; ++k4) {
        float4 xv = xr[k4];
        int k = k4 * 4;
        acc = fmaf(xv.x, W1[(k + 0) * HID_CH + lane], acc);
        acc = fmaf(xv.y, W1[(k + 1) * HID_CH + lane], acc);
        acc = fmaf(xv.z, W1[(k + 2) * HID_CH + lane], acc);
        acc = fmaf(xv.w, W1[(k + 3) * HID_CH + lane], acc);
    }
    xs[(size_t)n * HID_CH + lane] = acc * rs[n];
}

// ---- pull aggregation layer 1: one wave per dest node, lane = channel ----
__global__ void k_agg1(const int* __restrict__ rowptr, const int* __restrict__ col,
                       const float* __restrict__ xs, float* __restrict__ agg1) {
    int gid = blockIdx.x * blockDim.x + threadIdx.x;
    int n = gid >> 6;
    int c = gid & 63;
    if (n >= NN) return;
    int beg = rowptr[n], end = rowptr[n + 1];
    float acc = xs[n * HID_CH + c];  // self-loop
    int i = beg;
    for (; i + 3 < end; i += 4) {
        int s0 = col[i], s1 = col[i + 1], s2 = col[i + 2], s3 = col[i + 3];
        acc += xs[s0 * HID_CH + c];
        acc += xs[s1 * HID_CH + c];
        acc += xs[s2 * HID_CH + c];
        acc += xs[s3 * HID_CH + c];
    }
    for (; i < end; ++i) acc += xs[col[i] * HID_CH + c];
    agg1[n * HID_CH + c] = acc;
}

// ---- h = relu(agg1*rs); ys = (h@W2 + b2)*rs; 32 threads per node ----
__global__ void k_gemm2(const float* __restrict__ agg1, const float* __restrict__ W2,
                        const float* __restrict__ b2, const float* __restrict__ rs,
                        float* __restrict__ ys) {
    int t = blockIdx.x * blockDim.x + threadIdx.x;
    int n = t >> 5;
    int c = t & 31;
    if (n >= NN) return;
    float rn = rs[n];
    float acc = b2[c];
    const float* a = agg1 + (size_t)n * HID_CH;
#pragma unroll
    for (int k = 0; k < HID_CH; ++k) {
        float h = a[k] * rn;
        h = h > 0.0f ? h : 0.0f;
        acc = fmaf(h, W2[k * OUT_CH + c], acc);
    }
    ys[(size_t)n * OUT_CH + c] = acc * rn;
}

// ---- pull aggregation layer 2 + final rs[d] scale: half-wave per node ----
__global__ void k_agg2(const int* __restrict__ rowptr, const int* __restrict__ col,
                       const float* __restrict__ ys, const float* __restrict__ rs,
                       float* __restrict__ out) {
    int gid = blockIdx.x * blockDim.x + threadIdx.x;
    int n = gid >> 5;
    int c = gid & 31;
    if (n >= NN) return;
    int beg = rowptr[n], end = rowptr[n + 1];
    float acc = ys[n * OUT_CH + c];  // self-loop
    int i = beg;
    for (; i + 3 < end; i += 4) {
        int s0 = col[i], s1 = col[i + 1], s2 = col[i + 2], s3 = col[i + 3];
        acc += ys[s0 * OUT_CH + c];
        acc += ys[s1 * OUT_CH + c];
        acc += ys[s2 * OUT_CH + c];
        acc += ys[s3 * OUT_CH + c];
    }
    for (; i < end; ++i) acc += ys[col[i] * OUT_CH + c];
    out[n * OUT_CH + c] = acc * rs[n];
}

extern "C" void kernel_launch(void* const* d_in, const int* in_sizes, int n_in,
                              void* d_out, int out_size, void* d_ws, size_t ws_size,
                              hipStream_t stream) {
    const float* x  = (const float*)d_in[0];
    const int*   ei = (const int*)d_in[1];  // (2, E): row 0 = src, row 1 = dst
    const float* W1 = (const float*)d_in[2];
    const float* b1 = (const float*)d_in[3];
    const float* W2 = (const float*)d_in[4];
    const float* b2 = (const float*)d_in[5];
    const int* sa = ei;
    const int* da = ei + NE;

    char* ws = (char*)d_ws;
    size_t off = 0;
    auto alloc = [&](size_t bytes) {
        void* p = ws + off;
        off += (bytes + 255) & ~(size_t)255;
        return p;
    };
    int*   hist   = (int*)alloc((size_t)NN * 4);
    int*   part   = (int*)alloc((size_t)NN * 4);
    int*   bsum   = (int*)alloc(128 * 4);
    int*   rowptr = (int*)alloc((size_t)(NN + 1) * 4);
    int*   cursor = (int*)alloc((size_t)NN * 4);
    int*   col    = (int*)alloc((size_t)NE * 4);
    float* rs     = (float*)alloc((size_t)NN * 4);
    float* xs     = (float*)alloc((size_t)NN * HID_CH * 4);
    float* agg1   = (float*)alloc((size_t)NN * HID_CH * 4);
    float* ys     = (float*)alloc((size_t)NN * OUT_CH * 4);
    float* outp   = (float*)d_out;

    const int B = 256;
    hipMemsetAsync(hist, 0, (size_t)NN * 4, stream);
    k_hist<<<(NE + B - 1) / B, B, 0, stream>>>(da, hist);
    k_rs<<<(NN + B - 1) / B, B, 0, stream>>>(hist, rs);
    k_scan1<<<NBLK_SCAN, 256, 0, stream>>>(hist, part, bsum);
    k_scan2<<<1, 128, 0, stream>>>(bsum);
    k_scan3<<<(NN + 1 + B - 1) / B, B, 0, stream>>>(part, bsum, rowptr, cursor);
    k_fill<<<(NE + B - 1) / B, B, 0, stream>>>(sa, da, cursor, col);

    k_gemm1<<<(NN + 3) / 4, B, 0, stream>>>(x, W1, b1, rs, xs);
    k_agg1<<<(NN * 64 + B - 1) / B, B, 0, stream>>>(rowptr, col, xs, agg1);
    k_gemm2<<<(NN + 7) / 8, B, 0, stream>>>(agg1, W2, b2, rs, ys);
    k_agg2<<<(NN * 32 + B - 1) / B, B, 0, stream>>>(rowptr, col, ys, rs, outp);
}

// Round 3
// 380.623 us; speedup vs baseline: 2.1656x; 1.4092x over previous
//
#include <hip/hip_runtime.h>

#define NN 100000
#define NE 1600000
#define IN_CH 128
#define HID_CH 64
#define OUT_CH 32
#define SCAN_CHUNK 1024
#define NBLK_SCAN ((NN + SCAN_CHUNK - 1) / SCAN_CHUNK)   // 98

// ---- degree histogram (no self-loop; +1 applied in k_rs) ----
__global__ void k_hist(const int* __restrict__ da, int* __restrict__ hist) {
    int e = blockIdx.x * blockDim.x + threadIdx.x;
    if (e < NE) atomicAdd(&hist[da[e]], 1);
}

__global__ void k_rs(const int* __restrict__ hist, float* __restrict__ rs) {
    int i = blockIdx.x * blockDim.x + threadIdx.x;
    if (i < NN) rs[i] = rsqrtf((float)(hist[i] + 1));
}

// ---- exclusive scan of hist -> rowptr ----
__global__ void k_scan1(const int* __restrict__ hist, int* __restrict__ part,
                        int* __restrict__ bsum) {
    __shared__ int lds[256];
    int t = threadIdx.x;
    int base = blockIdx.x * SCAN_CHUNK + t * 4;
    int v0 = 0, v1 = 0, v2 = 0, v3 = 0;
    if (base + 0 < NN) v0 = hist[base + 0];
    if (base + 1 < NN) v1 = hist[base + 1];
    if (base + 2 < NN) v2 = hist[base + 2];
    if (base + 3 < NN) v3 = hist[base + 3];
    int s = v0 + v1 + v2 + v3;
    lds[t] = s;
    __syncthreads();
    for (int off = 1; off < 256; off <<= 1) {
        int x = (t >= off) ? lds[t - off] : 0;
        __syncthreads();
        lds[t] += x;
        __syncthreads();
    }
    int excl = lds[t] - s;
    if (base + 0 < NN) part[base + 0] = excl;
    if (base + 1 < NN) part[base + 1] = excl + v0;
    if (base + 2 < NN) part[base + 2] = excl + v0 + v1;
    if (base + 3 < NN) part[base + 3] = excl + v0 + v1 + v2;
    if (t == 255) bsum[blockIdx.x] = lds[255];
}

__global__ void k_scan2(int* __restrict__ bsum) {  // single block
    __shared__ int lds[128];
    int t = threadIdx.x;
    int v = (t < NBLK_SCAN) ? bsum[t] : 0;
    lds[t] = v;
    __syncthreads();
    for (int off = 1; off < 128; off <<= 1) {
        int x = (t >= off) ? lds[t - off] : 0;
        __syncthreads();
        lds[t] += x;
        __syncthreads();
    }
    if (t < NBLK_SCAN) bsum[t] = lds[t] - v;  // exclusive
}

__global__ void k_scan3(const int* __restrict__ part, const int* __restrict__ bsum,
                        int* __restrict__ rowptr, int* __restrict__ cursor) {
    int i = blockIdx.x * blockDim.x + threadIdx.x;
    if (i < NN) {
        int v = part[i] + bsum[i >> 10];
        rowptr[i] = v;
        cursor[i] = v;
    }
    if (i == NN) rowptr[NN] = NE;
}

__global__ void k_fill(const int* __restrict__ sa, const int* __restrict__ da,
                       int* __restrict__ cursor, int* __restrict__ col) {
    int e = blockIdx.x * blockDim.x + threadIdx.x;
    if (e < NE) {
        int p = atomicAdd(&cursor[da[e]], 1);
        col[p] = sa[e];
    }
}

// XOR swizzle: keeps 4-float groups contiguous & 16B aligned, spreads banks.
#define SWZ1(n, k) ((n) * 128 + ((k) ^ ((((n) & 7)) << 2)))
#define SWZ2(n, k) ((n) * 64 + ((k) ^ ((((n) & 7)) << 2)))

// ---- tiled GEMM1: xs[n][c] = ((x[n] @ W1 + b1)[c]) * rs[n] ----
// 64 nodes/block, 256 threads; thread owns 4 nodes (tn+16j) x 4 channels.
__global__ __launch_bounds__(256) void k_gemm1(
    const float* __restrict__ x, const float* __restrict__ W1,
    const float* __restrict__ b1, const float* __restrict__ rs,
    float* __restrict__ xs) {
    __shared__ float xt[64 * 128];   // 32 KB, swizzled
    __shared__ float w1s[128 * 64];  // 32 KB
    int t = threadIdx.x;
    int base = blockIdx.x * 64;

#pragma unroll
    for (int i = 0; i < 8; ++i) {
        int flat = i * 1024 + t * 4;
        int node = flat >> 7, k0 = flat & 127;
        int gn = base + node;
        float4 v = make_float4(0.f, 0.f, 0.f, 0.f);
        if (gn < NN) v = *(const float4*)(x + (size_t)gn * IN_CH + k0);
        *(float4*)&xt[SWZ1(node, k0)] = v;
        *(float4*)&w1s[flat] = *(const float4*)(W1 + flat);
    }
    __syncthreads();

    int tn = t & 15, tc = t >> 4;
    int c0 = tc * 4;
    float acc[4][4];
#pragma unroll
    for (int a = 0; a < 4; ++a)
#pragma unroll
        for (int b = 0; b < 4; ++b) acc[a][b] = 0.f;

    for (int k0 = 0; k0 < 128; k0 += 4) {
        float xq[4][4], wq[4][4];
#pragma unroll
        for (int j = 0; j < 4; ++j)
            *(float4*)&wq[j][0] = *(float4*)&w1s[(k0 + j) * 64 + c0];
#pragma unroll
        for (int jn = 0; jn < 4; ++jn)
            *(float4*)&xq[jn][0] = *(float4*)&xt[SWZ1(tn + jn * 16, k0)];
#pragma unroll
        for (int jn = 0; jn < 4; ++jn)
#pragma unroll
            for (int j = 0; j < 4; ++j)
#pragma unroll
                for (int jc = 0; jc < 4; ++jc)
                    acc[jn][jc] = fmaf(xq[jn][j], wq[j][jc], acc[jn][jc]);
    }

    float4 bb = *(const float4*)&b1[c0];
#pragma unroll
    for (int jn = 0; jn < 4; ++jn) {
        int gn = base + tn + jn * 16;
        if (gn < NN) {
            float r = rs[gn];
            float4 o;
            o.x = (acc[jn][0] + bb.x) * r;
            o.y = (acc[jn][1] + bb.y) * r;
            o.z = (acc[jn][2] + bb.z) * r;
            o.w = (acc[jn][3] + bb.w) * r;
            *(float4*)&xs[(size_t)gn * HID_CH + c0] = o;
        }
    }
}

// ---- pull aggregation layer 1 + relu + rs scale (h for layer 2) ----
__global__ void k_agg1(const int* __restrict__ rowptr, const int* __restrict__ col,
                       const float* __restrict__ xs, const float* __restrict__ rs,
                       float* __restrict__ h) {
    int gid = blockIdx.x * blockDim.x + threadIdx.x;
    int n = gid >> 6;
    int c = gid & 63;
    if (n >= NN) return;
    int beg = rowptr[n], end = rowptr[n + 1];
    float acc = xs[n * HID_CH + c];  // self-loop
    int i = beg;
    for (; i + 3 < end; i += 4) {
        int s0 = col[i], s1 = col[i + 1], s2 = col[i + 2], s3 = col[i + 3];
        acc += xs[s0 * HID_CH + c];
        acc += xs[s1 * HID_CH + c];
        acc += xs[s2 * HID_CH + c];
        acc += xs[s3 * HID_CH + c];
    }
    for (; i < end; ++i) acc += xs[col[i] * HID_CH + c];
    h[n * HID_CH + c] = fmaxf(acc * rs[n], 0.f);  // relu(rs * agg)
}

// ---- tiled GEMM2: ys[n][c] = ((h[n] @ W2 + b2)[c]) * rs[n] ----
// 64 nodes/block, 256 threads; thread owns 4 nodes x 2 channels.
__global__ __launch_bounds__(256) void k_gemm2(
    const float* __restrict__ h, const float* __restrict__ W2,
    const float* __restrict__ b2, const float* __restrict__ rs,
    float* __restrict__ ys) {
    __shared__ float ht[64 * 64];   // 16 KB, swizzled
    __shared__ float w2s[64 * 32];  // 8 KB
    int t = threadIdx.x;
    int base = blockIdx.x * 64;

#pragma unroll
    for (int i = 0; i < 4; ++i) {
        int flat = i * 1024 + t * 4;
        int node = flat >> 6, k0 = flat & 63;
        int gn = base + node;
        float4 v = make_float4(0.f, 0.f, 0.f, 0.f);
        if (gn < NN) v = *(const float4*)(h + (size_t)gn * HID_CH + k0);
        *(float4*)&ht[SWZ2(node, k0)] = v;
    }
#pragma unroll
    for (int i = 0; i < 2; ++i) {
        int flat = i * 1024 + t * 4;
        *(float4*)&w2s[flat] = *(const float4*)(W2 + flat);
    }
    __syncthreads();

    int tn = t & 15, tc = t >> 4;
    int c0 = tc * 2;
    float acc[4][2];
#pragma unroll
    for (int a = 0; a < 4; ++a) { acc[a][0] = 0.f; acc[a][1] = 0.f; }

    for (int k0 = 0; k0 < 64; k0 += 4) {
        float xq[4][4], wq[4][2];
#pragma unroll
        for (int j = 0; j < 4; ++j)
            *(float2*)&wq[j][0] = *(float2*)&w2s[(k0 + j) * 32 + c0];
#pragma unroll
        for (int jn = 0; jn < 4; ++jn)
            *(float4*)&xq[jn][0] = *(float4*)&ht[SWZ2(tn + jn * 16, k0)];
#pragma unroll
        for (int jn = 0; jn < 4; ++jn)
#pragma unroll
            for (int j = 0; j < 4; ++j) {
                acc[jn][0] = fmaf(xq[jn][j], wq[j][0], acc[jn][0]);
                acc[jn][1] = fmaf(xq[jn][j], wq[j][1], acc[jn][1]);
            }
    }

    float2 bb = *(const float2*)&b2[c0];
#pragma unroll
    for (int jn = 0; jn < 4; ++jn) {
        int gn = base + tn + jn * 16;
        if (gn < NN) {
            float r = rs[gn];
            float2 o;
            o.x = (acc[jn][0] + bb.x) * r;
            o.y = (acc[jn][1] + bb.y) * r;
            *(float2*)&ys[(size_t)gn * OUT_CH + c0] = o;
        }
    }
}

// ---- pull aggregation layer 2 + final rs[d] scale ----
__global__ void k_agg2(const int* __restrict__ rowptr, const int* __restrict__ col,
                       const float* __restrict__ ys, const float* __restrict__ rs,
                       float* __restrict__ out) {
    int gid = blockIdx.x * blockDim.x + threadIdx.x;
    int n = gid >> 5;
    int c = gid & 31;
    if (n >= NN) return;
    int beg = rowptr[n], end = rowptr[n + 1];
    float acc = ys[n * OUT_CH + c];  // self-loop
    int i = beg;
    for (; i + 3 < end; i += 4) {
        int s0 = col[i], s1 = col[i + 1], s2 = col[i + 2], s3 = col[i + 3];
        acc += ys[s0 * OUT_CH + c];
        acc += ys[s1 * OUT_CH + c];
        acc += ys[s2 * OUT_CH + c];
        acc += ys[s3 * OUT_CH + c];
    }
    for (; i < end; ++i) acc += ys[col[i] * OUT_CH + c];
    out[n * OUT_CH + c] = acc * rs[n];
}

extern "C" void kernel_launch(void* const* d_in, const int* in_sizes, int n_in,
                              void* d_out, int out_size, void* d_ws, size_t ws_size,
                              hipStream_t stream) {
    const float* x  = (const float*)d_in[0];
    const int*   ei = (const int*)d_in[1];  // (2, E): row 0 = src, row 1 = dst
    const float* W1 = (const float*)d_in[2];
    const float* b1 = (const float*)d_in[3];
    const float* W2 = (const float*)d_in[4];
    const float* b2 = (const float*)d_in[5];
    const int* sa = ei;
    const int* da = ei + NE;

    char* ws = (char*)d_ws;
    size_t off = 0;
    auto alloc = [&](size_t bytes) {
        void* p = ws + off;
        off += (bytes + 255) & ~(size_t)255;
        return p;
    };
    int*   hist   = (int*)alloc((size_t)NN * 4);
    int*   part   = (int*)alloc((size_t)NN * 4);
    int*   bsum   = (int*)alloc(128 * 4);
    int*   rowptr = (int*)alloc((size_t)(NN + 1) * 4);
    int*   cursor = (int*)alloc((size_t)NN * 4);
    int*   col    = (int*)alloc((size_t)NE * 4);
    float* rs     = (float*)alloc((size_t)NN * 4);
    float* xs     = (float*)alloc((size_t)NN * HID_CH * 4);
    float* hbuf   = (float*)alloc((size_t)NN * HID_CH * 4);
    float* ys     = (float*)alloc((size_t)NN * OUT_CH * 4);
    float* outp   = (float*)d_out;

    const int B = 256;
    hipMemsetAsync(hist, 0, (size_t)NN * 4, stream);
    k_hist<<<(NE + B - 1) / B, B, 0, stream>>>(da, hist);
    k_rs<<<(NN + B - 1) / B, B, 0, stream>>>(hist, rs);
    k_scan1<<<NBLK_SCAN, 256, 0, stream>>>(hist, part, bsum);
    k_scan2<<<1, 128, 0, stream>>>(bsum);
    k_scan3<<<(NN + 1 + B - 1) / B, B, 0, stream>>>(part, bsum, rowptr, cursor);
    k_fill<<<(NE + B - 1) / B, B, 0, stream>>>(sa, da, cursor, col);

    const int NBLK_GEMM = (NN + 63) / 64;  // 1563
    k_gemm1<<<NBLK_GEMM, 256, 0, stream>>>(x, W1, b1, rs, xs);
    k_agg1<<<(NN * 64 + B - 1) / B, B, 0, stream>>>(rowptr, col, xs, rs, hbuf);
    k_gemm2<<<NBLK_GEMM, 256, 0, stream>>>(hbuf, W2, b2, rs, ys);
    k_agg2<<<(NN * 32 + B - 1) / B, B, 0, stream>>>(rowptr, col, ys, rs, outp);
}

// Round 4
// 247.458 us; speedup vs baseline: 3.3310x; 1.5381x over previous
//
#include <hip/hip_runtime.h>

#define NN 100000
#define NE 1600000
#define IN_CH 128
#define HID_CH 64
#define OUT_CH 32
#define NBUCK 391            // ceil(NN/256) coarse buckets of 256 nodes
#define CHUNKA 8192          // edges per block in bucket pass

// ---- coarse bucket histogram (dst>>8) ----
__global__ __launch_bounds__(256) void k_bhist(const int* __restrict__ da,
                                               int* __restrict__ bcnt) {
    __shared__ int hist[NBUCK];
    int t = threadIdx.x;
    for (int i = t; i < NBUCK; i += 256) hist[i] = 0;
    __syncthreads();
    int base = blockIdx.x * CHUNKA;
    for (int i = 0; i < CHUNKA; i += 256) {
        int e = base + i + t;
        if (e < NE) atomicAdd(&hist[da[e] >> 8], 1);
    }
    __syncthreads();
    for (int i = t; i < NBUCK; i += 256) {
        int c = hist[i];
        if (c) atomicAdd(&bcnt[i], c);
    }
}

// ---- scan bucket counts -> bucket bases & cursors (one block) ----
__global__ __launch_bounds__(512) void k_bscan(const int* __restrict__ bcnt,
                                               int* __restrict__ bbase,
                                               int* __restrict__ bcur,
                                               int* __restrict__ rowptr) {
    __shared__ int lds[512];
    int t = threadIdx.x;
    int v = (t < NBUCK) ? bcnt[t] : 0;
    lds[t] = v;
    __syncthreads();
    for (int off = 1; off < 512; off <<= 1) {
        int x = (t >= off) ? lds[t - off] : 0;
        __syncthreads();
        lds[t] += x;
        __syncthreads();
    }
    int excl = lds[t] - v;
    if (t < NBUCK) { bbase[t] = excl; bcur[t] = excl; }
    if (t == 0) { bbase[NBUCK] = NE; rowptr[NN] = NE; }
}

// ---- bucket fill: per-(block,bucket) contiguous runs, packed (src<<8|dlow) ----
__global__ __launch_bounds__(256) void k_bfill(const int* __restrict__ sa,
                                               const int* __restrict__ da,
                                               int* __restrict__ bcur,
                                               unsigned* __restrict__ ebuf) {
    __shared__ int hist[NBUCK];
    __shared__ int lcur[NBUCK];
    int t = threadIdx.x;
    for (int i = t; i < NBUCK; i += 256) hist[i] = 0;
    __syncthreads();
    int base = blockIdx.x * CHUNKA;
    for (int i = 0; i < CHUNKA; i += 256) {
        int e = base + i + t;
        if (e < NE) atomicAdd(&hist[da[e] >> 8], 1);
    }
    __syncthreads();
    for (int b = t; b < NBUCK; b += 256) {
        int c = hist[b];
        lcur[b] = c ? atomicAdd(&bcur[b], c) : 0;
    }
    __syncthreads();
    for (int i = 0; i < CHUNKA; i += 256) {
        int e = base + i + t;
        if (e < NE) {
            int d = da[e];
            int p = atomicAdd(&lcur[d >> 8], 1);
            ebuf[p] = ((unsigned)sa[e] << 8) | (unsigned)(d & 255);
        }
    }
}

// ---- fine pass: one block per bucket -> rowptr, rs, col ----
__global__ __launch_bounds__(256) void k_bfine(const unsigned* __restrict__ ebuf,
                                               const int* __restrict__ bbase,
                                               int* __restrict__ rowptr,
                                               float* __restrict__ rs,
                                               int* __restrict__ col) {
    __shared__ int cnt[256];
    __shared__ int cur[256];
    __shared__ int scn[256];
    int b = blockIdx.x, t = threadIdx.x;
    int nb = NN - b * 256; if (nb > 256) nb = 256;
    int beg = bbase[b], end = bbase[b + 1];
    cnt[t] = 0;
    __syncthreads();
    for (int i = beg + t; i < end; i += 256) atomicAdd(&cnt[ebuf[i] & 255], 1);
    __syncthreads();
    int v = cnt[t];
    scn[t] = v;
    __syncthreads();
    for (int off = 1; off < 256; off <<= 1) {
        int x = (t >= off) ? scn[t - off] : 0;
        __syncthreads();
        scn[t] += x;
        __syncthreads();
    }
    int excl = scn[t] - v;
    if (t < nb) {
        rowptr[b * 256 + t] = beg + excl;
        rs[b * 256 + t] = rsqrtf((float)(v + 1));
        cur[t] = beg + excl;
    }
    __syncthreads();
    for (int i = beg + t; i < end; i += 256) {
        unsigned p = ebuf[i];
        int pos = atomicAdd(&cur[p & 255], 1);
        col[pos] = (int)(p >> 8);
    }
}

// XOR swizzle: keeps 4-float groups contiguous & 16B aligned, spreads banks.
#define SWZ1(n, k) ((n) * 128 + ((k) ^ ((((n) & 7)) << 2)))
#define SWZ2(n, k) ((n) * 64 + ((k) ^ ((((n) & 7)) << 2)))

// ---- tiled GEMM1: xs[n][c] = ((x[n] @ W1 + b1)[c]) * rs[n] ----
__global__ __launch_bounds__(256) void k_gemm1(
    const float* __restrict__ x, const float* __restrict__ W1,
    const float* __restrict__ b1, const float* __restrict__ rs,
    float* __restrict__ xs) {
    __shared__ float xt[64 * 128];   // 32 KB, swizzled
    __shared__ float w1s[128 * 64];  // 32 KB
    int t = threadIdx.x;
    int base = blockIdx.x * 64;

#pragma unroll
    for (int i = 0; i < 8; ++i) {
        int flat = i * 1024 + t * 4;
        int node = flat >> 7, k0 = flat & 127;
        int gn = base + node;
        float4 v = make_float4(0.f, 0.f, 0.f, 0.f);
        if (gn < NN) v = *(const float4*)(x + (size_t)gn * IN_CH + k0);
        *(float4*)&xt[SWZ1(node, k0)] = v;
        *(float4*)&w1s[flat] = *(const float4*)(W1 + flat);
    }
    __syncthreads();

    int tn = t & 15, tc = t >> 4;
    int c0 = tc * 4;
    float acc[4][4];
#pragma unroll
    for (int a = 0; a < 4; ++a)
#pragma unroll
        for (int b = 0; b < 4; ++b) acc[a][b] = 0.f;

    for (int k0 = 0; k0 < 128; k0 += 4) {
        float xq[4][4], wq[4][4];
#pragma unroll
        for (int j = 0; j < 4; ++j)
            *(float4*)&wq[j][0] = *(float4*)&w1s[(k0 + j) * 64 + c0];
#pragma unroll
        for (int jn = 0; jn < 4; ++jn)
            *(float4*)&xq[jn][0] = *(float4*)&xt[SWZ1(tn + jn * 16, k0)];
#pragma unroll
        for (int jn = 0; jn < 4; ++jn)
#pragma unroll
            for (int j = 0; j < 4; ++j)
#pragma unroll
                for (int jc = 0; jc < 4; ++jc)
                    acc[jn][jc] = fmaf(xq[jn][j], wq[j][jc], acc[jn][jc]);
    }

    float4 bb = *(const float4*)&b1[c0];
#pragma unroll
    for (int jn = 0; jn < 4; ++jn) {
        int gn = base + tn + jn * 16;
        if (gn < NN) {
            float r = rs[gn];
            float4 o;
            o.x = (acc[jn][0] + bb.x) * r;
            o.y = (acc[jn][1] + bb.y) * r;
            o.z = (acc[jn][2] + bb.z) * r;
            o.w = (acc[jn][3] + bb.w) * r;
            *(float4*)&xs[(size_t)gn * HID_CH + c0] = o;
        }
    }
}

// ---- pull aggregation layer 1 + relu + rs scale ----
__global__ void k_agg1(const int* __restrict__ rowptr, const int* __restrict__ col,
                       const float* __restrict__ xs, const float* __restrict__ rs,
                       float* __restrict__ h) {
    int gid = blockIdx.x * blockDim.x + threadIdx.x;
    int n = gid >> 6;
    int c = gid & 63;
    if (n >= NN) return;
    int beg = rowptr[n], end = rowptr[n + 1];
    float acc = xs[n * HID_CH + c];  // self-loop
    int i = beg;
    for (; i + 3 < end; i += 4) {
        int s0 = col[i], s1 = col[i + 1], s2 = col[i + 2], s3 = col[i + 3];
        acc += xs[s0 * HID_CH + c];
        acc += xs[s1 * HID_CH + c];
        acc += xs[s2 * HID_CH + c];
        acc += xs[s3 * HID_CH + c];
    }
    for (; i < end; ++i) acc += xs[col[i] * HID_CH + c];
    h[n * HID_CH + c] = fmaxf(acc * rs[n], 0.f);
}

// ---- tiled GEMM2: ys[n][c] = ((h[n] @ W2 + b2)[c]) * rs[n] ----
__global__ __launch_bounds__(256) void k_gemm2(
    const float* __restrict__ h, const float* __restrict__ W2,
    const float* __restrict__ b2, const float* __restrict__ rs,
    float* __restrict__ ys) {
    __shared__ float ht[64 * 64];   // 16 KB, swizzled
    __shared__ float w2s[64 * 32];  // 8 KB
    int t = threadIdx.x;
    int base = blockIdx.x * 64;

#pragma unroll
    for (int i = 0; i < 4; ++i) {
        int flat = i * 1024 + t * 4;
        int node = flat >> 6, k0 = flat & 63;
        int gn = base + node;
        float4 v = make_float4(0.f, 0.f, 0.f, 0.f);
        if (gn < NN) v = *(const float4*)(h + (size_t)gn * HID_CH + k0);
        *(float4*)&ht[SWZ2(node, k0)] = v;
    }
#pragma unroll
    for (int i = 0; i < 2; ++i) {
        int flat = i * 1024 + t * 4;
        *(float4*)&w2s[flat] = *(const float4*)(W2 + flat);
    }
    __syncthreads();

    int tn = t & 15, tc = t >> 4;
    int c0 = tc * 2;
    float acc[4][2];
#pragma unroll
    for (int a = 0; a < 4; ++a) { acc[a][0] = 0.f; acc[a][1] = 0.f; }

    for (int k0 = 0; k0 < 64; k0 += 4) {
        float xq[4][4], wq[4][2];
#pragma unroll
        for (int j = 0; j < 4; ++j)
            *(float2*)&wq[j][0] = *(float2*)&w2s[(k0 + j) * 32 + c0];
#pragma unroll
        for (int jn = 0; jn < 4; ++jn)
            *(float4*)&xq[jn][0] = *(float4*)&ht[SWZ2(tn + jn * 16, k0)];
#pragma unroll
        for (int jn = 0; jn < 4; ++jn)
#pragma unroll
            for (int j = 0; j < 4; ++j) {
                acc[jn][0] = fmaf(xq[jn][j], wq[j][0], acc[jn][0]);
                acc[jn][1] = fmaf(xq[jn][j], wq[j][1], acc[jn][1]);
            }
    }

    float2 bb = *(const float2*)&b2[c0];
#pragma unroll
    for (int jn = 0; jn < 4; ++jn) {
        int gn = base + tn + jn * 16;
        if (gn < NN) {
            float r = rs[gn];
            float2 o;
            o.x = (acc[jn][0] + bb.x) * r;
            o.y = (acc[jn][1] + bb.y) * r;
            *(float2*)&ys[(size_t)gn * OUT_CH + c0] = o;
        }
    }
}

// ---- pull aggregation layer 2 + final rs[d] scale ----
__global__ void k_agg2(const int* __restrict__ rowptr, const int* __restrict__ col,
                       const float* __restrict__ ys, const float* __restrict__ rs,
                       float* __restrict__ out) {
    int gid = blockIdx.x * blockDim.x + threadIdx.x;
    int n = gid >> 5;
    int c = gid & 31;
    if (n >= NN) return;
    int beg = rowptr[n], end = rowptr[n + 1];
    float acc = ys[n * OUT_CH + c];  // self-loop
    int i = beg;
    for (; i + 3 < end; i += 4) {
        int s0 = col[i], s1 = col[i + 1], s2 = col[i + 2], s3 = col[i + 3];
        acc += ys[s0 * OUT_CH + c];
        acc += ys[s1 * OUT_CH + c];
        acc += ys[s2 * OUT_CH + c];
        acc += ys[s3 * OUT_CH + c];
    }
    for (; i < end; ++i) acc += ys[col[i] * OUT_CH + c];
    out[n * OUT_CH + c] = acc * rs[n];
}

extern "C" void kernel_launch(void* const* d_in, const int* in_sizes, int n_in,
                              void* d_out, int out_size, void* d_ws, size_t ws_size,
                              hipStream_t stream) {
    const float* x  = (const float*)d_in[0];
    const int*   ei = (const int*)d_in[1];  // (2, E): row 0 = src, row 1 = dst
    const float* W1 = (const float*)d_in[2];
    const float* b1 = (const float*)d_in[3];
    const float* W2 = (const float*)d_in[4];
    const float* b2 = (const float*)d_in[5];
    const int* sa = ei;
    const int* da = ei + NE;

    char* ws = (char*)d_ws;
    size_t off = 0;
    auto alloc = [&](size_t bytes) {
        void* p = ws + off;
        off += (bytes + 255) & ~(size_t)255;
        return p;
    };
    int*      bcnt   = (int*)alloc((size_t)NBUCK * 4);
    int*      bbase  = (int*)alloc((size_t)(NBUCK + 1) * 4);
    int*      bcur   = (int*)alloc((size_t)NBUCK * 4);
    int*      rowptr = (int*)alloc((size_t)(NN + 1) * 4);
    float*    rs     = (float*)alloc((size_t)NN * 4);
    unsigned* ebuf   = (unsigned*)alloc((size_t)NE * 4);
    int*      col    = (int*)alloc((size_t)NE * 4);
    float*    xs     = (float*)alloc((size_t)NN * HID_CH * 4);
    float*    hbuf   = (float*)alloc((size_t)NN * HID_CH * 4);
    float*    ys     = xs;  // xs dead after k_agg1; reuse for ys
    float*    outp   = (float*)d_out;

    const int B = 256;
    const int NBLKA = (NE + CHUNKA - 1) / CHUNKA;  // 196
    hipMemsetAsync(bcnt, 0, (size_t)NBUCK * 4, stream);
    k_bhist<<<NBLKA, 256, 0, stream>>>(da, bcnt);
    k_bscan<<<1, 512, 0, stream>>>(bcnt, bbase, bcur, rowptr);
    k_bfill<<<NBLKA, 256, 0, stream>>>(sa, da, bcur, ebuf);
    k_bfine<<<NBUCK, 256, 0, stream>>>(ebuf, bbase, rowptr, rs, col);

    const int NBLK_GEMM = (NN + 63) / 64;  // 1563
    k_gemm1<<<NBLK_GEMM, 256, 0, stream>>>(x, W1, b1, rs, xs);
    k_agg1<<<(NN * 64 + B - 1) / B, B, 0, stream>>>(rowptr, col, xs, rs, hbuf);
    k_gemm2<<<NBLK_GEMM, 256, 0, stream>>>(hbuf, W2, b2, rs, ys);
    k_agg2<<<(NN * 32 + B - 1) / B, B, 0, stream>>>(rowptr, col, ys, rs, outp);
}

// Round 5
// 242.453 us; speedup vs baseline: 3.3997x; 1.0206x over previous
//
#include <hip/hip_runtime.h>

#define NN 100000
#define NE 1600000
#define IN_CH 128
#define HID_CH 64
#define OUT_CH 32
#define NBUCK 391            // ceil(NN/256) coarse buckets of 256 nodes
#define CHUNKA 8192          // edges per block in bucket pass

typedef unsigned short ushort_t;

__device__ inline ushort_t f2bf(float f) {  // round-to-nearest-even
    union { float f; unsigned u; } v; v.f = f;
    unsigned r = v.u + 0x7fff + ((v.u >> 16) & 1);
    return (ushort_t)(r >> 16);
}
__device__ inline float bf2f(ushort_t h) {
    union { unsigned u; float f; } v; v.u = ((unsigned)h) << 16;
    return v.f;
}

// ---- coarse bucket histogram (dst>>8) ----
__global__ __launch_bounds__(256) void k_bhist(const int* __restrict__ da,
                                               int* __restrict__ bcnt) {
    __shared__ int hist[NBUCK];
    int t = threadIdx.x;
    for (int i = t; i < NBUCK; i += 256) hist[i] = 0;
    __syncthreads();
    int base = blockIdx.x * CHUNKA;
    for (int i = 0; i < CHUNKA; i += 256) {
        int e = base + i + t;
        if (e < NE) atomicAdd(&hist[da[e] >> 8], 1);
    }
    __syncthreads();
    for (int i = t; i < NBUCK; i += 256) {
        int c = hist[i];
        if (c) atomicAdd(&bcnt[i], c);
    }
}

// ---- scan bucket counts -> bucket bases & cursors (one block) ----
__global__ __launch_bounds__(512) void k_bscan(const int* __restrict__ bcnt,
                                               int* __restrict__ bbase,
                                               int* __restrict__ bcur,
                                               int* __restrict__ rowptr) {
    __shared__ int lds[512];
    int t = threadIdx.x;
    int v = (t < NBUCK) ? bcnt[t] : 0;
    lds[t] = v;
    __syncthreads();
    for (int off = 1; off < 512; off <<= 1) {
        int x = (t >= off) ? lds[t - off] : 0;
        __syncthreads();
        lds[t] += x;
        __syncthreads();
    }
    int excl = lds[t] - v;
    if (t < NBUCK) { bbase[t] = excl; bcur[t] = excl; }
    if (t == 0) { bbase[NBUCK] = NE; rowptr[NN] = NE; }
}

// ---- bucket fill: per-(block,bucket) contiguous runs, packed (src<<8|dlow) ----
__global__ __launch_bounds__(256) void k_bfill(const int* __restrict__ sa,
                                               const int* __restrict__ da,
                                               int* __restrict__ bcur,
                                               unsigned* __restrict__ ebuf) {
    __shared__ int hist[NBUCK];
    __shared__ int lcur[NBUCK];
    int t = threadIdx.x;
    for (int i = t; i < NBUCK; i += 256) hist[i] = 0;
    __syncthreads();
    int base = blockIdx.x * CHUNKA;
    for (int i = 0; i < CHUNKA; i += 256) {
        int e = base + i + t;
        if (e < NE) atomicAdd(&hist[da[e] >> 8], 1);
    }
    __syncthreads();
    for (int b = t; b < NBUCK; b += 256) {
        int c = hist[b];
        lcur[b] = c ? atomicAdd(&bcur[b], c) : 0;
    }
    __syncthreads();
    for (int i = 0; i < CHUNKA; i += 256) {
        int e = base + i + t;
        if (e < NE) {
            int d = da[e];
            int p = atomicAdd(&lcur[d >> 8], 1);
            ebuf[p] = ((unsigned)sa[e] << 8) | (unsigned)(d & 255);
        }
    }
}

// ---- fine pass: one block per bucket -> rowptr, rs, col ----
__global__ __launch_bounds__(256) void k_bfine(const unsigned* __restrict__ ebuf,
                                               const int* __restrict__ bbase,
                                               int* __restrict__ rowptr,
                                               float* __restrict__ rs,
                                               int* __restrict__ col) {
    __shared__ int cnt[256];
    __shared__ int cur[256];
    __shared__ int scn[256];
    int b = blockIdx.x, t = threadIdx.x;
    int nb = NN - b * 256; if (nb > 256) nb = 256;
    int beg = bbase[b], end = bbase[b + 1];
    cnt[t] = 0;
    __syncthreads();
    for (int i = beg + t; i < end; i += 256) atomicAdd(&cnt[ebuf[i] & 255], 1);
    __syncthreads();
    int v = cnt[t];
    scn[t] = v;
    __syncthreads();
    for (int off = 1; off < 256; off <<= 1) {
        int x = (t >= off) ? scn[t - off] : 0;
        __syncthreads();
        scn[t] += x;
        __syncthreads();
    }
    int excl = scn[t] - v;
    if (t < nb) {
        rowptr[b * 256 + t] = beg + excl;
        rs[b * 256 + t] = rsqrtf((float)(v + 1));
        cur[t] = beg + excl;
    }
    __syncthreads();
    for (int i = beg + t; i < end; i += 256) {
        unsigned p = ebuf[i];
        int pos = atomicAdd(&cur[p & 255], 1);
        col[pos] = (int)(p >> 8);
    }
}

// XOR swizzle: keeps 4-float groups contiguous & 16B aligned, spreads banks.
#define SWZ1(n, k) ((n) * 128 + ((k) ^ ((((n) & 7)) << 2)))
#define SWZ2(n, k) ((n) * 64 + ((k) ^ ((((n) & 7)) << 2)))

// ---- tiled GEMM1: xsb[n][c] = bf16(((x[n] @ W1 + b1)[c]) * rs[n]) ----
__global__ __launch_bounds__(256) void k_gemm1(
    const float* __restrict__ x, const float* __restrict__ W1,
    const float* __restrict__ b1, const float* __restrict__ rs,
    ushort_t* __restrict__ xsb) {
    __shared__ float xt[64 * 128];   // 32 KB, swizzled
    __shared__ float w1s[128 * 64];  // 32 KB
    int t = threadIdx.x;
    int base = blockIdx.x * 64;

#pragma unroll
    for (int i = 0; i < 8; ++i) {
        int flat = i * 1024 + t * 4;
        int node = flat >> 7, k0 = flat & 127;
        int gn = base + node;
        float4 v = make_float4(0.f, 0.f, 0.f, 0.f);
        if (gn < NN) v = *(const float4*)(x + (size_t)gn * IN_CH + k0);
        *(float4*)&xt[SWZ1(node, k0)] = v;
        *(float4*)&w1s[flat] = *(const float4*)(W1 + flat);
    }
    __syncthreads();

    int tn = t & 15, tc = t >> 4;
    int c0 = tc * 4;
    float acc[4][4];
#pragma unroll
    for (int a = 0; a < 4; ++a)
#pragma unroll
        for (int b = 0; b < 4; ++b) acc[a][b] = 0.f;

    for (int k0 = 0; k0 < 128; k0 += 4) {
        float xq[4][4], wq[4][4];
#pragma unroll
        for (int j = 0; j < 4; ++j)
            *(float4*)&wq[j][0] = *(float4*)&w1s[(k0 + j) * 64 + c0];
#pragma unroll
        for (int jn = 0; jn < 4; ++jn)
            *(float4*)&xq[jn][0] = *(float4*)&xt[SWZ1(tn + jn * 16, k0)];
#pragma unroll
        for (int jn = 0; jn < 4; ++jn)
#pragma unroll
            for (int j = 0; j < 4; ++j)
#pragma unroll
                for (int jc = 0; jc < 4; ++jc)
                    acc[jn][jc] = fmaf(xq[jn][j], wq[j][jc], acc[jn][jc]);
    }

    float4 bb = *(const float4*)&b1[c0];
#pragma unroll
    for (int jn = 0; jn < 4; ++jn) {
        int gn = base + tn + jn * 16;
        if (gn < NN) {
            float r = rs[gn];
            uint2 pk;
            pk.x = (unsigned)f2bf((acc[jn][0] + bb.x) * r) |
                   ((unsigned)f2bf((acc[jn][1] + bb.y) * r) << 16);
            pk.y = (unsigned)f2bf((acc[jn][2] + bb.z) * r) |
                   ((unsigned)f2bf((acc[jn][3] + bb.w) * r) << 16);
            *(uint2*)&xsb[(size_t)gn * HID_CH + c0] = pk;
        }
    }
}

// ---- pull aggregation layer 1 (bf16 gather) + relu + rs scale ----
__global__ void k_agg1(const int* __restrict__ rowptr, const int* __restrict__ col,
                       const ushort_t* __restrict__ xsb, const float* __restrict__ rs,
                       float* __restrict__ h) {
    int gid = blockIdx.x * blockDim.x + threadIdx.x;
    int n = gid >> 6;
    int c = gid & 63;
    if (n >= NN) return;
    int beg = rowptr[n], end = rowptr[n + 1];
    float acc = bf2f(xsb[n * HID_CH + c]);  // self-loop
    int i = beg;
    for (; i + 3 < end; i += 4) {
        int s0 = col[i], s1 = col[i + 1], s2 = col[i + 2], s3 = col[i + 3];
        acc += bf2f(xsb[s0 * HID_CH + c]);
        acc += bf2f(xsb[s1 * HID_CH + c]);
        acc += bf2f(xsb[s2 * HID_CH + c]);
        acc += bf2f(xsb[s3 * HID_CH + c]);
    }
    for (; i < end; ++i) acc += bf2f(xsb[col[i] * HID_CH + c]);
    h[n * HID_CH + c] = fmaxf(acc * rs[n], 0.f);
}

// ---- tiled GEMM2: ysb[n][c] = bf16(((h[n] @ W2 + b2)[c]) * rs[n]) ----
__global__ __launch_bounds__(256) void k_gemm2(
    const float* __restrict__ h, const float* __restrict__ W2,
    const float* __restrict__ b2, const float* __restrict__ rs,
    ushort_t* __restrict__ ysb) {
    __shared__ float ht[64 * 64];   // 16 KB, swizzled
    __shared__ float w2s[64 * 32];  // 8 KB
    int t = threadIdx.x;
    int base = blockIdx.x * 64;

#pragma unroll
    for (int i = 0; i < 4; ++i) {
        int flat = i * 1024 + t * 4;
        int node = flat >> 6, k0 = flat & 63;
        int gn = base + node;
        float4 v = make_float4(0.f, 0.f, 0.f, 0.f);
        if (gn < NN) v = *(const float4*)(h + (size_t)gn * HID_CH + k0);
        *(float4*)&ht[SWZ2(node, k0)] = v;
    }
#pragma unroll
    for (int i = 0; i < 2; ++i) {
        int flat = i * 1024 + t * 4;
        *(float4*)&w2s[flat] = *(const float4*)(W2 + flat);
    }
    __syncthreads();

    int tn = t & 15, tc = t >> 4;
    int c0 = tc * 2;
    float acc[4][2];
#pragma unroll
    for (int a = 0; a < 4; ++a) { acc[a][0] = 0.f; acc[a][1] = 0.f; }

    for (int k0 = 0; k0 < 64; k0 += 4) {
        float xq[4][4], wq[4][2];
#pragma unroll
        for (int j = 0; j < 4; ++j)
            *(float2*)&wq[j][0] = *(float2*)&w2s[(k0 + j) * 32 + c0];
#pragma unroll
        for (int jn = 0; jn < 4; ++jn)
            *(float4*)&xq[jn][0] = *(float4*)&ht[SWZ2(tn + jn * 16, k0)];
#pragma unroll
        for (int jn = 0; jn < 4; ++jn)
#pragma unroll
            for (int j = 0; j < 4; ++j) {
                acc[jn][0] = fmaf(xq[jn][j], wq[j][0], acc[jn][0]);
                acc[jn][1] = fmaf(xq[jn][j], wq[j][1], acc[jn][1]);
            }
    }

    float2 bb = *(const float2*)&b2[c0];
#pragma unroll
    for (int jn = 0; jn < 4; ++jn) {
        int gn = base + tn + jn * 16;
        if (gn < NN) {
            float r = rs[gn];
            unsigned pk = (unsigned)f2bf((acc[jn][0] + bb.x) * r) |
                          ((unsigned)f2bf((acc[jn][1] + bb.y) * r) << 16);
            *(unsigned*)&ysb[(size_t)gn * OUT_CH + c0] = pk;
        }
    }
}

// ---- pull aggregation layer 2 (bf16 gather) + final rs[d] scale ----
__global__ void k_agg2(const int* __restrict__ rowptr, const int* __restrict__ col,
                       const ushort_t* __restrict__ ysb, const float* __restrict__ rs,
                       float* __restrict__ out) {
    int gid = blockIdx.x * blockDim.x + threadIdx.x;
    int n = gid >> 5;
    int c = gid & 31;
    if (n >= NN) return;
    int beg = rowptr[n], end = rowptr[n + 1];
    float acc = bf2f(ysb[n * OUT_CH + c]);  // self-loop
    int i = beg;
    for (; i + 3 < end; i += 4) {
        int s0 = col[i], s1 = col[i + 1], s2 = col[i + 2], s3 = col[i + 3];
        acc += bf2f(ysb[s0 * OUT_CH + c]);
        acc += bf2f(ysb[s1 * OUT_CH + c]);
        acc += bf2f(ysb[s2 * OUT_CH + c]);
        acc += bf2f(ysb[s3 * OUT_CH + c]);
    }
    for (; i < end; ++i) acc += bf2f(ysb[col[i] * OUT_CH + c]);
    out[n * OUT_CH + c] = acc * rs[n];
}

extern "C" void kernel_launch(void* const* d_in, const int* in_sizes, int n_in,
                              void* d_out, int out_size, void* d_ws, size_t ws_size,
                              hipStream_t stream) {
    const float* x  = (const float*)d_in[0];
    const int*   ei = (const int*)d_in[1];  // (2, E): row 0 = src, row 1 = dst
    const float* W1 = (const float*)d_in[2];
    const float* b1 = (const float*)d_in[3];
    const float* W2 = (const float*)d_in[4];
    const float* b2 = (const float*)d_in[5];
    const int* sa = ei;
    const int* da = ei + NE;

    char* ws = (char*)d_ws;
    size_t off = 0;
    auto alloc = [&](size_t bytes) {
        void* p = ws + off;
        off += (bytes + 255) & ~(size_t)255;
        return p;
    };
    int*      bcnt   = (int*)alloc((size_t)NBUCK * 4);
    int*      bbase  = (int*)alloc((size_t)(NBUCK + 1) * 4);
    int*      bcur   = (int*)alloc((size_t)NBUCK * 4);
    int*      rowptr = (int*)alloc((size_t)(NN + 1) * 4);
    float*    rs     = (float*)alloc((size_t)NN * 4);
    unsigned* ebuf   = (unsigned*)alloc((size_t)NE * 4);
    int*      col    = (int*)alloc((size_t)NE * 4);
    ushort_t* xsb    = (ushort_t*)alloc((size_t)NN * HID_CH * 2);  // 12.8 MB
    float*    hbuf   = (float*)alloc((size_t)NN * HID_CH * 4);     // 25.6 MB
    ushort_t* ysb    = xsb;  // xsb dead after k_agg1; reuse for ysb
    float*    outp   = (float*)d_out;

    const int B = 256;
    const int NBLKA = (NE + CHUNKA - 1) / CHUNKA;  // 196
    hipMemsetAsync(bcnt, 0, (size_t)NBUCK * 4, stream);
    k_bhist<<<NBLKA, 256, 0, stream>>>(da, bcnt);
    k_bscan<<<1, 512, 0, stream>>>(bcnt, bbase, bcur, rowptr);
    k_bfill<<<NBLKA, 256, 0, stream>>>(sa, da, bcur, ebuf);
    k_bfine<<<NBUCK, 256, 0, stream>>>(ebuf, bbase, rowptr, rs, col);

    const int NBLK_GEMM = (NN + 63) / 64;  // 1563
    k_gemm1<<<NBLK_GEMM, 256, 0, stream>>>(x, W1, b1, rs, xsb);
    k_agg1<<<(NN * 64 + B - 1) / B, B, 0, stream>>>(rowptr, col, xsb, rs, hbuf);
    k_gemm2<<<NBLK_GEMM, 256, 0, stream>>>(hbuf, W2, b2, rs, ysb);
    k_agg2<<<(NN * 32 + B - 1) / B, B, 0, stream>>>(rowptr, col, ysb, rs, outp);
}